// Round 2
// baseline (136.198 us; speedup 1.0000x reference)
//
#include <hip/hip_runtime.h>

#define Bv 256
#define Tv 200
#define Cv 40
#define H1v 512
#define H2v 256
#define Ov 12
#define THv 1.0f
// Conservative speculation threshold: if no unit's speculative v1 ever reaches
// 0.9, then (fp32 rounding ~1e-6 << 0.1 margin) no unit ever reaches 1.0 in the
// exact dynamics either -> no spikes anywhere -> output is exactly zero.
#define SPEC_TH 0.90f

typedef unsigned long long u64;

// ---------------------------------------------------------------------------
// One block per batch element, 512 threads (8 waves), thread tid owns unit h=tid.
//
// PHASE 1 (fast, speculative): on the no-spike trajectory a1 == 0 and layer 1
// decouples into 512 independent scalar EMAs:
//     v1(t) = al1*v1(t-1) + (1-al1)*dot(x_t, W1[h])
// x_t is WAVE-UNIFORM -> read it through the scalar pipe (s_load via uniform
// address off the const __restrict__ arg), NOT LDS. R1 post-mortem: 10
// ds_read_b128/thread-step = 80 LDS wave-instrs/CU/step on the single LDS
// pipe ~= 960 cy/step = the entire 72 us. Scalar x reads cost 0 VALU / 0 LDS;
// the dot is 40x v_fmac_f32 vC, sX, vW.
// Each thread tracks max v1; one block reduce decides:
//   max < SPEC_TH  -> provably no spikes -> out = 0, done.
//   otherwise      -> PHASE 2: exact coupled simulation (harness-verified
//                     pipelined kernel), correct for arbitrary spiking data.
// ---------------------------------------------------------------------------
__global__ __launch_bounds__(512) void snn_main(
    const float* __restrict__ x,
    const float* __restrict__ W1,
    const float* __restrict__ Wrec,
    const float* __restrict__ W2,
    const float* __restrict__ Wout,
    const float* __restrict__ alpha1, const float* __restrict__ rho1, const float* __restrict__ ba1,
    const float* __restrict__ alpha2, const float* __restrict__ rho2, const float* __restrict__ ba2,
    const float* __restrict__ beta_out,
    float* __restrict__ out)
{
    __shared__ __align__(16) u64 s_m1[2][8];           // spk1 masks (exact path)
    __shared__ __align__(16) u64 s_m2[2][4];           // spk2 masks (exact path)
    __shared__ __align__(16) u64 s_red[8];             // spec-phase any-spike reduce

    const int b    = blockIdx.x;
    const int tid  = threadIdx.x;
    const int lane = tid & 63;

    // --- per-thread W1 row in registers (40 floats = 10 float4) ---
    float4 w1r[10];
    {
        const float4* p = (const float4*)(W1 + tid * Cv);
        #pragma unroll
        for (int i = 0; i < 10; ++i) w1r[i] = p[i];
    }
    const float al1 = alpha1[tid];
    const float k1  = 1.f - al1;

    // Uniform base for this block's x slice (scalar-pipe reads).
    const float* __restrict__ xb = x + (size_t)b * (Tv * Cv);

    // ================= PHASE 1: barrier-free speculative scan =================
    {
        float v1 = 0.f, vmax = 0.f;
        #pragma unroll 2
        for (int t = 0; t < Tv; ++t) {
            const float* __restrict__ xr = xb + t * Cv;   // uniform address
            float c0 = 0.f, c1 = 0.f, c2 = 0.f, c3 = 0.f;
            #pragma unroll
            for (int i = 0; i < 10; ++i) {
                // uniform scalar loads -> s_load_dwordx4/x8; FMA takes SGPR src
                const float x0 = xr[4*i+0];
                const float x1 = xr[4*i+1];
                const float x2 = xr[4*i+2];
                const float x3 = xr[4*i+3];
                c0 += x0 * w1r[i].x;
                c1 += x1 * w1r[i].y;
                c2 += x2 * w1r[i].z;
                c3 += x3 * w1r[i].w;
            }
            const float acc = (c0 + c1) + (c2 + c3);
            v1 = al1 * v1 + k1 * acc;
            vmax = fmaxf(vmax, v1);
        }

        const u64 bal = __ballot(vmax >= SPEC_TH);
        if (lane == 0) s_red[tid >> 6] = bal;
        __syncthreads();
        u64 any = 0ull;
        #pragma unroll
        for (int i = 0; i < 8; ++i) any |= s_red[i];
        if (any == 0ull) {
            // Provably spike-free: every downstream signal is exactly zero.
            if (tid < Ov) out[b * Ov + tid] = 0.f;
            return;
        }
    }

    // ================= PHASE 2: exact coupled simulation (rare) ===============
    // Identical dynamics to the harness-verified pipelined kernel; x is read
    // through the same uniform scalar path.
    const float rh1 = rho1[tid], bb1 = ba1[tid];
    float v1 = 0.f, a1 = 0.f, spk1 = 0.f;
    float al2 = 0.f, rh2 = 0.f, bb2 = 0.f, v2 = 0.f, a2 = 0.f;
    if (tid < H2v) { al2 = alpha2[tid]; rh2 = rho2[tid]; bb2 = ba2[tid]; }
    const float beta = beta_out[0];
    float vout = 0.f, osum = 0.f;

    if (tid < 8) { s_m1[0][tid] = 0ull; s_m1[1][tid] = 0ull; }
    if (tid < 4) { s_m2[0][tid] = 0ull; s_m2[1][tid] = 0ull; }
    __syncthreads();

    for (int t = 0; t < Tv + 2; ++t) {
        const int cur = t & 1, prev = cur ^ 1;

        u64 m1[8];
        #pragma unroll
        for (int i = 0; i < 8; ++i) m1[i] = s_m1[prev][i];
        u64 anyw = 0;
        #pragma unroll
        for (int i = 0; i < 8; ++i) anyw |= m1[i];
        const bool any1 = (anyw != 0ull);

        const bool doOut = (tid < Ov) & (t >= 2);
        u64 m2[4] = {0ull, 0ull, 0ull, 0ull};
        if (doOut) {
            #pragma unroll
            for (int i = 0; i < 4; ++i) m2[i] = s_m2[prev][i];
        }

        // ---- L1 update for step t ----
        if (t < Tv) {
            const float* __restrict__ xr = xb + t * Cv;   // uniform address
            float c0 = 0.f, c1 = 0.f, c2 = 0.f, c3 = 0.f;
            #pragma unroll
            for (int i = 0; i < 10; ++i) {
                const float x0 = xr[4*i+0];
                const float x1 = xr[4*i+1];
                const float x2 = xr[4*i+2];
                const float x3 = xr[4*i+3];
                c0 += x0 * w1r[i].x;
                c1 += x1 * w1r[i].y;
                c2 += x2 * w1r[i].z;
                c3 += x3 * w1r[i].w;
            }
            float acc = (c0 + c1) + (c2 + c3);
            if (any1) {
                #pragma unroll
                for (int w = 0; w < 8; ++w) {
                    u64 m = m1[w];
                    while (m) {
                        const int j = (w << 6) + __builtin_ctzll(m);
                        m &= (m - 1);
                        acc += Wrec[tid * H1v + j];
                    }
                }
            }
            v1 = al1 * (v1 - spk1 * THv) + (1.f - al1) * (acc - a1);
            const bool sp = (v1 >= THv);
            spk1 = sp ? 1.f : 0.f;
            a1 = rh1 * a1 + bb1 * spk1;
            const u64 bal = __ballot(sp);
            if (lane == 0) s_m1[cur][tid >> 6] = bal;
        }

        // ---- L2 update for step t-1 ----
        if ((tid < H2v) & (t >= 1) & (t <= Tv)) {
            float acc2 = 0.f;
            if (any1) {
                #pragma unroll
                for (int w = 0; w < 8; ++w) {
                    u64 m = m1[w];
                    while (m) {
                        const int j = (w << 6) + __builtin_ctzll(m);
                        m &= (m - 1);
                        acc2 += W2[tid * H1v + j];
                    }
                }
            }
            v2 = al2 * v2 + (1.f - al2) * (acc2 - a2);
            const bool sp2 = (v2 >= THv);
            a2 = rh2 * a2 + bb2 * (sp2 ? 1.f : 0.f);
            const u64 bal2 = __ballot(sp2);
            if (lane == 0) s_m2[cur][tid >> 6] = bal2;
        }

        // ---- Out update for step t-2 ----
        if (doOut) {
            float io = 0.f;
            if (m2[0] | m2[1] | m2[2] | m2[3]) {
                #pragma unroll
                for (int w = 0; w < 4; ++w) {
                    u64 m = m2[w];
                    while (m) {
                        const int j = (w << 6) + __builtin_ctzll(m);
                        m &= (m - 1);
                        io += Wout[tid * H2v + j];
                    }
                }
            }
            vout = beta * vout + (1.f - beta) * io;
            osum += vout;
        }

        __syncthreads();
    }

    if (tid < Ov) out[b * Ov + tid] = osum / (float)Tv;
}

extern "C" void kernel_launch(void* const* d_in, const int* in_sizes, int n_in,
                              void* d_out, int out_size, void* d_ws, size_t ws_size,
                              hipStream_t stream)
{
    const float* x       = (const float*)d_in[0];
    const float* W1      = (const float*)d_in[1];
    const float* Wrec    = (const float*)d_in[2];
    const float* W2      = (const float*)d_in[3];
    const float* Wout    = (const float*)d_in[4];
    const float* alpha1  = (const float*)d_in[5];
    const float* rho1    = (const float*)d_in[6];
    const float* ba1     = (const float*)d_in[7];
    const float* alpha2  = (const float*)d_in[8];
    const float* rho2    = (const float*)d_in[9];
    const float* ba2     = (const float*)d_in[10];
    const float* beta_o  = (const float*)d_in[11];
    float* out = (float*)d_out;

    snn_main<<<dim3(Bv), dim3(512), 0, stream>>>(
        x, W1, Wrec, W2, Wout,
        alpha1, rho1, ba1, alpha2, rho2, ba2, beta_o, out);
}

// Round 4
// 127.209 us; speedup vs baseline: 1.0707x; 1.0707x over previous
//
#include <hip/hip_runtime.h>

#define Bv 256
#define Tv 200
#define Cv 40
#define H1v 512
#define H2v 256
#define Ov 12
#define THv 1.0f
// Conservative speculation threshold: if no unit's speculative v1 ever reaches
// 0.9, then (fp32 rounding ~1e-6 << 0.1 margin) no unit ever reaches 1.0 in the
// exact dynamics either -> no spikes anywhere -> output is exactly zero.
#define SPEC_TH 0.90f

typedef unsigned long long u64;

// ---------------------------------------------------------------------------
// One block per batch element, 512 threads (8 waves).
//
// PHASE 1 (speculative, barrier-free): on the no-spike trajectory layer 1
// decouples into independent scalar EMAs. R1 post-mortem established the LDS
// broadcast pipe as the floor: every participating thread must read all 8000
// x floats (2000 ds_read_b128), so per-CU LDS cycles = waves x 2000 x 12cy.
// Fix: only waves 0-1 participate (128 threads), each owning FOUR hidden
// units (tid, tid+128, tid+256, tid+384). LDS traffic drops 4x (8 waves ->
// 2 waves); the 4x VALU work per thread runs on 2 SIMDs as packed-friendly
// float4 FMAs, concurrent with the LDS reads. Waves 2-7 idle (no LDS issue).
// Each thread tracks max v1 over its 4 units; block reduce gates:
//   max < SPEC_TH -> provably no spikes -> out = 0, done.
//   else          -> PHASE 2: exact coupled simulation (R1 harness-verified,
//                    512 threads, 1 unit each), correct for any spiking data.
// ---------------------------------------------------------------------------
__global__ __launch_bounds__(512) void snn_main(
    const float* __restrict__ x,
    const float* __restrict__ W1,
    const float* __restrict__ Wrec,
    const float* __restrict__ W2,
    const float* __restrict__ Wout,
    const float* __restrict__ alpha1, const float* __restrict__ rho1, const float* __restrict__ ba1,
    const float* __restrict__ alpha2, const float* __restrict__ rho2, const float* __restrict__ ba2,
    const float* __restrict__ beta_out,
    float* __restrict__ out)
{
    __shared__ __align__(16) float lds_x[Tv * Cv];     // 32000 B fp32 x slice
    __shared__ __align__(16) u64 s_m1[2][8];           // spk1 masks (exact path)
    __shared__ __align__(16) u64 s_m2[2][4];           // spk2 masks (exact path)
    __shared__ __align__(16) u64 s_red[8];             // spec-phase any-spike reduce

    const int b    = blockIdx.x;
    const int tid  = threadIdx.x;
    const int lane = tid & 63;
    const int wid  = tid >> 6;

    // --- stage this block's x slice into LDS (coalesced float4), once ---
    {
        const float4* xg = (const float4*)(x + (size_t)b * (Tv * Cv));
        float4* xl = (float4*)lds_x;
        for (int i = tid; i < (Tv * Cv) / 4; i += 512) xl[i] = xg[i];
    }
    __syncthreads();

    // ================= PHASE 1: 2-wave speculative scan =================
    float vmax = 0.f;
    if (tid < 128) {
        // 4 W1 rows in registers: units tid + 128*u  (40 floats each)
        float4 w0[10], w1r[10], w2r[10], w3r[10];
        {
            const float4* p0 = (const float4*)(W1 + (tid      ) * Cv);
            const float4* p1 = (const float4*)(W1 + (tid + 128) * Cv);
            const float4* p2 = (const float4*)(W1 + (tid + 256) * Cv);
            const float4* p3 = (const float4*)(W1 + (tid + 384) * Cv);
            #pragma unroll
            for (int i = 0; i < 10; ++i) { w0[i] = p0[i]; w1r[i] = p1[i]; w2r[i] = p2[i]; w3r[i] = p3[i]; }
        }
        const float a0 = alpha1[tid],       k0 = 1.f - a0;
        const float a1 = alpha1[tid + 128], k1 = 1.f - a1;
        const float a2 = alpha1[tid + 256], k2 = 1.f - a2;
        const float a3 = alpha1[tid + 384], k3 = 1.f - a3;
        float v0 = 0.f, v1 = 0.f, v2 = 0.f, v3 = 0.f;

        for (int t = 0; t < Tv; ++t) {
            const float4* xr = (const float4*)(&lds_x[t * Cv]);
            float4 s0 = {0.f,0.f,0.f,0.f}, s1 = {0.f,0.f,0.f,0.f};
            float4 s2 = {0.f,0.f,0.f,0.f}, s3 = {0.f,0.f,0.f,0.f};
            #pragma unroll
            for (int i = 0; i < 10; ++i) {
                const float4 xv = xr[i];
                s0.x += xv.x * w0[i].x;  s0.y += xv.y * w0[i].y;
                s0.z += xv.z * w0[i].z;  s0.w += xv.w * w0[i].w;
                s1.x += xv.x * w1r[i].x; s1.y += xv.y * w1r[i].y;
                s1.z += xv.z * w1r[i].z; s1.w += xv.w * w1r[i].w;
                s2.x += xv.x * w2r[i].x; s2.y += xv.y * w2r[i].y;
                s2.z += xv.z * w2r[i].z; s2.w += xv.w * w2r[i].w;
                s3.x += xv.x * w3r[i].x; s3.y += xv.y * w3r[i].y;
                s3.z += xv.z * w3r[i].z; s3.w += xv.w * w3r[i].w;
            }
            const float d0 = (s0.x + s0.y) + (s0.z + s0.w);
            const float d1 = (s1.x + s1.y) + (s1.z + s1.w);
            const float d2 = (s2.x + s2.y) + (s2.z + s2.w);
            const float d3 = (s3.x + s3.y) + (s3.z + s3.w);
            v0 = a0 * v0 + k0 * d0;
            v1 = a1 * v1 + k1 * d1;
            v2 = a2 * v2 + k2 * d2;
            v3 = a3 * v3 + k3 * d3;
            vmax = fmaxf(vmax, fmaxf(fmaxf(v0, v1), fmaxf(v2, v3)));
        }
    }

    {
        const u64 bal = __ballot(vmax >= SPEC_TH);   // all 8 waves execute; waves 2-7 ballot 0
        if (lane == 0) s_red[wid] = bal;
        __syncthreads();
        u64 any = 0ull;
        #pragma unroll
        for (int i = 0; i < 8; ++i) any |= s_red[i];
        if (any == 0ull) {
            // Provably spike-free: every downstream signal is exactly zero.
            if (tid < Ov) out[b * Ov + tid] = 0.f;
            return;
        }
    }

    // ================= PHASE 2: exact coupled simulation (rare) ===============
    // Verbatim R1 harness-verified pipelined kernel (512 threads, 1 unit each);
    // lds_x still holds the fp32 x slice.
    float4 w1r[10];
    {
        const float4* p = (const float4*)(W1 + tid * Cv);
        #pragma unroll
        for (int i = 0; i < 10; ++i) w1r[i] = p[i];
    }
    const float al1 = alpha1[tid];
    const float rh1 = rho1[tid], bb1 = ba1[tid];
    float v1 = 0.f, a1 = 0.f, spk1 = 0.f;
    float al2 = 0.f, rh2 = 0.f, bb2 = 0.f, v2 = 0.f, a2 = 0.f;
    if (tid < H2v) { al2 = alpha2[tid]; rh2 = rho2[tid]; bb2 = ba2[tid]; }
    const float beta = beta_out[0];
    float vout = 0.f, osum = 0.f;

    if (tid < 8) { s_m1[0][tid] = 0ull; s_m1[1][tid] = 0ull; }
    if (tid < 4) { s_m2[0][tid] = 0ull; s_m2[1][tid] = 0ull; }
    __syncthreads();

    for (int t = 0; t < Tv + 2; ++t) {
        const int cur = t & 1, prev = cur ^ 1;

        u64 m1[8];
        #pragma unroll
        for (int i = 0; i < 8; ++i) m1[i] = s_m1[prev][i];
        u64 anyw = 0;
        #pragma unroll
        for (int i = 0; i < 8; ++i) anyw |= m1[i];
        const bool any1 = (anyw != 0ull);

        const bool doOut = (tid < Ov) & (t >= 2);
        u64 m2[4] = {0ull, 0ull, 0ull, 0ull};
        if (doOut) {
            #pragma unroll
            for (int i = 0; i < 4; ++i) m2[i] = s_m2[prev][i];
        }

        // ---- L1 update for step t ----
        if (t < Tv) {
            const float4* xr = (const float4*)(&lds_x[t * Cv]);
            float c0 = 0.f, c1 = 0.f, c2 = 0.f, c3 = 0.f;
            #pragma unroll
            for (int i = 0; i < 10; ++i) {
                const float4 xv = xr[i];
                c0 += xv.x * w1r[i].x;
                c1 += xv.y * w1r[i].y;
                c2 += xv.z * w1r[i].z;
                c3 += xv.w * w1r[i].w;
            }
            float acc = (c0 + c1) + (c2 + c3);
            if (any1) {
                #pragma unroll
                for (int w = 0; w < 8; ++w) {
                    u64 m = m1[w];
                    while (m) {
                        const int j = (w << 6) + __builtin_ctzll(m);
                        m &= (m - 1);
                        acc += Wrec[tid * H1v + j];
                    }
                }
            }
            v1 = al1 * (v1 - spk1 * THv) + (1.f - al1) * (acc - a1);
            const bool sp = (v1 >= THv);
            spk1 = sp ? 1.f : 0.f;
            a1 = rh1 * a1 + bb1 * spk1;
            const u64 bal = __ballot(sp);
            if (lane == 0) s_m1[cur][tid >> 6] = bal;
        }

        // ---- L2 update for step t-1 ----
        if ((tid < H2v) & (t >= 1) & (t <= Tv)) {
            float acc2 = 0.f;
            if (any1) {
                #pragma unroll
                for (int w = 0; w < 8; ++w) {
                    u64 m = m1[w];
                    while (m) {
                        const int j = (w << 6) + __builtin_ctzll(m);
                        m &= (m - 1);
                        acc2 += W2[tid * H1v + j];
                    }
                }
            }
            v2 = al2 * v2 + (1.f - al2) * (acc2 - a2);
            const bool sp2 = (v2 >= THv);
            a2 = rh2 * a2 + bb2 * (sp2 ? 1.f : 0.f);
            const u64 bal2 = __ballot(sp2);
            if (lane == 0) s_m2[cur][tid >> 6] = bal2;
        }

        // ---- Out update for step t-2 ----
        if (doOut) {
            float io = 0.f;
            if (m2[0] | m2[1] | m2[2] | m2[3]) {
                #pragma unroll
                for (int w = 0; w < 4; ++w) {
                    u64 m = m2[w];
                    while (m) {
                        const int j = (w << 6) + __builtin_ctzll(m);
                        m &= (m - 1);
                        io += Wout[tid * H2v + j];
                    }
                }
            }
            vout = beta * vout + (1.f - beta) * io;
            osum += vout;
        }

        __syncthreads();
    }

    if (tid < Ov) out[b * Ov + tid] = osum / (float)Tv;
}

extern "C" void kernel_launch(void* const* d_in, const int* in_sizes, int n_in,
                              void* d_out, int out_size, void* d_ws, size_t ws_size,
                              hipStream_t stream)
{
    const float* x       = (const float*)d_in[0];
    const float* W1      = (const float*)d_in[1];
    const float* Wrec    = (const float*)d_in[2];
    const float* W2      = (const float*)d_in[3];
    const float* Wout    = (const float*)d_in[4];
    const float* alpha1  = (const float*)d_in[5];
    const float* rho1    = (const float*)d_in[6];
    const float* ba1     = (const float*)d_in[7];
    const float* alpha2  = (const float*)d_in[8];
    const float* rho2    = (const float*)d_in[9];
    const float* ba2     = (const float*)d_in[10];
    const float* beta_o  = (const float*)d_in[11];
    float* out = (float*)d_out;

    snn_main<<<dim3(Bv), dim3(512), 0, stream>>>(
        x, W1, Wrec, W2, Wout,
        alpha1, rho1, ba1, alpha2, rho2, ba2, beta_o, out);
}